// Round 13
// baseline (126.078 us; speedup 1.0000x reference)
//
#include <hip/hip_runtime.h>

#define TREES 32
#define NIPT  511
#define NINT  (TREES*NIPT)      // 16352
#define VLEAF 5000

typedef __bf16 bf16_t;
typedef bf16_t bf16x4 __attribute__((ext_vector_type(4)));
typedef bf16_t bf16x8 __attribute__((ext_vector_type(8)));
typedef float  f32x4  __attribute__((ext_vector_type(4)));

__device__ __forceinline__ float sigf(float x) { return 1.0f/(1.0f+__expf(-x)); }
__device__ __forceinline__ float tanh_fast(float x) { return 2.0f/(1.0f+__expf(-2.0f*x)) - 1.0f; }

__device__ __forceinline__ bf16x8 to_bf16x8(const float* p) {
  float4 a = *(const float4*)p;
  float4 b = *(const float4*)(p+4);
  bf16x8 r;
  r[0]=(bf16_t)a.x; r[1]=(bf16_t)a.y; r[2]=(bf16_t)a.z; r[3]=(bf16_t)a.w;
  r[4]=(bf16_t)b.x; r[5]=(bf16_t)b.y; r[6]=(bf16_t)b.z; r[7]=(bf16_t)b.w;
  return r;
}
__device__ __forceinline__ bf16x8 zero_bf16x8() {
  bf16x8 r;
  #pragma unroll
  for (int i=0;i<8;++i) r[i]=(bf16_t)0.0f;
  return r;
}
__device__ __forceinline__ bf16x8 ldsB(const char* lds, int col, int kb, int rowb) {
  return *(const bf16x8*)(lds + col*rowb + kb);
}

// ---- staging (1024-thread variants): fp32 src columns -> bf16 N-major LDS ----
__device__ __forceinline__ void stage_WU_1k(const float* __restrict__ Wa, int lda,
                                            const float* __restrict__ Wb, int ldb,
                                            char* lds, int tid) {
  int col = tid & 511, kh = tid >> 9;            // two threads split each column's k
  const float* src; int ld;
  if (col < 384) { src = Wa + col; ld = lda; }
  else           { src = Wb + (col-384); ld = ldb; }
  const int kbase = kh*64;
  #pragma unroll
  for (int k0 = 0; k0 < 64; k0 += 8) {
    bf16x8 r;
    #pragma unroll
    for (int i=0;i<8;++i) r[i] = (bf16_t)src[(kbase+k0+i)*ld];
    *(bf16x8*)(lds + col*264 + (kbase+k0)*2) = r;
  }
}
__device__ __forceinline__ void stage_WL_1k(const float* __restrict__ W_leaf, char* lds, int tid) {
  int col = tid & 511, kh = tid >> 9;
  if (col < 384) {
    int cm = col < 128 ? col : col + 128;        // [gi,gg,go] from [gi,gf,gg,go]
    const int kbase = kh*96;
    #pragma unroll
    for (int k0 = 0; k0 < 96; k0 += 8) {
      bf16x8 r;
      #pragma unroll
      for (int i=0;i<8;++i) {
        int k = kbase+k0+i;
        r[i] = (bf16_t)W_leaf[(k>>6)*32768 + (k&63)*512 + cm];
      }
      *(bf16x8*)(lds + col*392 + (kbase+k0)*2) = r;
    }
  }
}
// ---- fast staging from pre-converted bf16 (512 threads, linear float4 copy)
template<int NCOLS, int KB, int ROWB>
__device__ __forceinline__ void stage_B(const bf16_t* __restrict__ src, char* lds, int tid) {
  const char* s = (const char*)src;
  for (int off = tid*16; off < NCOLS*KB; off += 512*16) {
    int col = off / KB;
    int ko  = off - col*KB;
    *(float4*)(lds + col*ROWB + ko) = *(const float4*)(s + off);
  }
}

// ---- 8-gate-slice MFMA from LDS-staged U
__device__ __forceinline__ void mfma8_lds(const char* Blds, const bf16x8 a[4],
                                          int cs, int lg, int col0, f32x4 acc[8]) {
  #pragma unroll
  for (int ks=0; ks<4; ++ks) {
    #pragma unroll
    for (int gs=0; gs<8; ++gs) {
      bf16x8 b = ldsB(Blds, (gs>>1)*128 + cs*32 + (gs&1)*16 + col0, ks*64 + lg*16, 264);
      acc[gs] = __builtin_amdgcn_mfma_f32_16x16x32_bf16(a[ks], b, acc[gs], 0,0,0);
    }
  }
}

// ---- LSTM combine for one (parent pp, slice s2); w4 = (i,o,u,f)
__device__ __forceinline__ void epi_one(const f32x4 acc[8], int pp, int s2,
                                        bf16x4 w4, float clv, float crv,
                                        float& hn, float& cn) {
  const int rb = 2*pp;
  float iv = acc[s2][rb]   + acc[s2][rb+1]   + (float)w4[0];
  float ov = acc[2+s2][rb] + acc[2+s2][rb+1] + (float)w4[1];
  float uv = acc[4+s2][rb] + acc[4+s2][rb+1] + (float)w4[2];
  float wf = (float)w4[3];
  float fl = sigf(acc[6+s2][rb]   + wf);
  float fr = sigf(acc[6+s2][rb+1] + wf);
  cn = sigf(iv)*tanh_fast(uv) + fl*clv + fr*crv;
  hn = sigf(ov)*tanh_fast(cn);
}

// =================== kernel 1: prep (blocks 0-127) | leaf (blocks 128-255) ====
// 1024 threads = 16 waves (4 rowgroups x 4 col-slices); folds Upt conversion
__global__ __launch_bounds__(1024) void k_prep_leaf(
    const int* __restrict__ features, const int* __restrict__ vocabs,
    const float* __restrict__ emb_res, const float* __restrict__ emb_leaf,
    const float* __restrict__ W_iou, const float* __restrict__ b_iou,
    const float* __restrict__ W_f, const float* __restrict__ b_f,
    const float* __restrict__ U_iou, const float* __restrict__ U_f,
    const float* __restrict__ W_leaf, const float* __restrict__ b_leaf,
    bf16_t* __restrict__ wx4, bf16_t* __restrict__ hg, float* __restrict__ c2,
    bf16_t* __restrict__ Upt)
{
  __shared__ __align__(16) char Blds[150528];
  const int tid = threadIdx.x, wave = tid>>6, lane = tid&63;
  const int rg = wave>>2, cs = wave&3, lg = lane>>4, col0 = lane&15;

  // fold: Upt[c][k] fp32->bf16 (N-major), 256 blocks x 256 threads = 65536 elems
  if (tid < 256) {
    int q = blockIdx.x*256 + tid;
    int cc = q>>7, k = q&127;
    Upt[q] = (bf16_t)(cc < 384 ? U_iou[k*384+cc] : U_f[k*128+cc-384]);
  }

  if (blockIdx.x < 128) {
    // ===== prep: wx4[ci][hcol][g] = bf16(emb@[W_iou|W_f]+bias), g={i,o,u,f}=cs
    stage_WU_1k(W_iou, 384, W_f, 128, Blds, tid);
    __syncthreads();
    #pragma unroll
    for (int mi=0; mi<2; ++mi) {
      int mt = rg + mi*4;
      int row0 = blockIdx.x*128 + mt*16;
      int rowA = row0 + (lane&15);
      if (rowA >= NINT) rowA = NINT-1;
      unsigned tree = (unsigned)rowA / 511u;
      int local = rowA - tree*511u;
      int feat = features[tree*1023 + local];
      const float* ep = emb_res + (size_t)feat*128 + lg*8;

      bf16x8 a[4];
      #pragma unroll
      for (int ks=0; ks<4; ++ks) a[ks] = to_bf16x8(ep + ks*32);

      f32x4 acc[8];
      #pragma unroll
      for (int j=0;j<8;++j) acc[j] = (f32x4){0.f,0.f,0.f,0.f};
      #pragma unroll
      for (int ks=0; ks<4; ++ks) {
        #pragma unroll
        for (int j=0; j<8; ++j) {
          bf16x8 b = ldsB(Blds, cs*128 + j*16 + col0, ks*64 + lg*16, 264);
          acc[j] = __builtin_amdgcn_mfma_f32_16x16x32_bf16(a[ks], b, acc[j], 0,0,0);
        }
      }
      #pragma unroll
      for (int j=0; j<8; ++j) {
        int hcol = j*16 + col0;
        int c = cs*128 + hcol;
        float bias = (c < 384) ? b_iou[c] : b_f[c-384];
        #pragma unroll
        for (int r=0; r<4; ++r) {
          int ci = row0 + lg*4 + r;
          if (ci >= NINT) ci = NINT-1;
          wx4[(size_t)ci*512 + hcol*4 + cs] = (bf16_t)(acc[j][r] + bias);
        }
      }
    }
  } else {
    // ===== leaf: block-diag K=192 GEMM, N=384 [gi|gg|go]; writes hg + paired c2
    stage_WL_1k(W_leaf, Blds, tid);
    __syncthreads();
    #pragma unroll
    for (int mi=0; mi<2; ++mi) {
      int mt = rg + mi*4;
      const int base = (int)(blockIdx.x-128)*128 + mt*16;
      int rA = base + (lane&15);
      int treeA = rA>>9, loA = rA&511;
      int nodeA = treeA*1023 + 511 + loA;
      int kkA = vocabs[nodeA]-1;
      int featA = features[nodeA];
      const float* xp = emb_leaf + ((size_t)kkA*VLEAF + featA)*64;

      f32x4 acc[6];
      #pragma unroll
      for (int j=0;j<6;++j) acc[j] = (f32x4){0.f,0.f,0.f,0.f};
      #pragma unroll
      for (int ks=0; ks<6; ++ks) {
        int k0 = ks*32 + lg*8;
        bf16x8 a = ((k0>>6) == kkA) ? to_bf16x8(xp + (k0&63)) : zero_bf16x8();
        #pragma unroll
        for (int g=0; g<3; ++g) {
          #pragma unroll
          for (int s=0; s<2; ++s) {
            bf16x8 b = ldsB(Blds, g*128 + cs*32 + s*16 + col0, ks*64 + lg*16, 392);
            acc[g*2+s] = __builtin_amdgcn_mfma_f32_16x16x32_bf16(a, b, acc[g*2+s], 0,0,0);
          }
        }
      }
      #pragma unroll
      for (int r=0; r<4; ++r) {
        int L = base + lg*4 + r;
        int tree = L>>9, lo = L&511;
        int l = 511 + lo;
        int node = tree*1023 + l;
        int kk = vocabs[node]-1;
        const float* bl = b_leaf + kk*512;
        int pl = l - 1;
        size_t c2b = ((size_t)tree*511 + (pl>>1))*256;
        #pragma unroll
        for (int s=0; s<2; ++s) {
          int cc = cs*32 + s*16 + col0;
          float gi = acc[s][r]   + bl[cc];
          float gg = acc[2+s][r] + bl[256+cc];
          float go = acc[4+s][r] + bl[384+cc];
          float ck = sigf(gi)*tanh_fast(gg);
          float hk = sigf(go)*tanh_fast(ck);
          c2[c2b + cc*2 + (pl&1)] = ck;
          hg[(size_t)node*128+cc] = (bf16_t)hk;
        }
      }
    }
  }
}

// =================== kernel 2: levels 1..6, all wx prefetched upfront =========
// 256 blocks (8/tree); U in LDS; st_h/st_c (bf16) in LDS; wx4/c2 vector loads
__global__ __launch_bounds__(512, 2) void k_levels(
    const bf16_t* __restrict__ Upt, const bf16_t* __restrict__ wx4,
    bf16_t* __restrict__ hg, float* __restrict__ c2)
{
  __shared__ __align__(16) char Blds[135168];          // 512 x 264
  __shared__ __align__(16) bf16_t st_h[48][132];       // 12672 B
  __shared__ __align__(16) bf16_t st_c[48][132];       // 12672 B  (total 160512)
  const int tid = threadIdx.x, wave = tid>>6, lane = tid&63;
  const int rg = wave>>2, cs = wave&3, lg = lane>>4, col0 = lane&15;
  const int blk = blockIdx.x, tree = blk>>3, b8 = blk&7;
  const size_t hb = (size_t)tree*1023, wbT = (size_t)tree*511;

  const int Pn_[4]   = {8, 4, 2, 1};
  const int cb_[4]   = {32, 0, 8, 12};     // child LDS row base (n=3..6)
  const int ob_[4]   = {0, 8, 12, 0};      // out LDS row base (li<3)
  const int base_[4] = {63, 31, 15, 7};    // parent plocal base
  const int mul_[4]  = {8, 4, 2, 1};       // parents per block

  // ---- upfront operand burst (all independent, before staging) ----
  bf16x4 w1[2][2][2]; float2 c1[2][2][2];
  #pragma unroll
  for (int mi=0; mi<2; ++mi) {
    int mt = rg + mi*2;
    #pragma unroll
    for (int pp=0; pp<2; ++pp) {
      int pl = 255 + b8*32 + mt*8 + lg*2 + pp;
      #pragma unroll
      for (int s2=0; s2<2; ++s2) {
        int hcol = cs*32 + s2*16 + col0;
        w1[mi][pp][s2] = *(const bf16x4*)(wx4 + ((wbT+pl)<<9) + hcol*4);
        c1[mi][pp][s2] = *(const float2*)(c2 + ((wbT+pl)<<8) + hcol*2);
      }
    }
  }
  bf16x4 w2[2][2];
  #pragma unroll
  for (int pp=0; pp<2; ++pp) {
    int pl = 127 + b8*16 + rg*8 + lg*2 + pp;
    #pragma unroll
    for (int s2=0; s2<2; ++s2) {
      int hcol = cs*32 + s2*16 + col0;
      w2[pp][s2] = *(const bf16x4*)(wx4 + ((wbT+pl)<<9) + hcol*4);
    }
  }
  bf16x4 w36[4][2][2];
  if (rg == 0) {
    #pragma unroll
    for (int li=0; li<4; ++li) {
      #pragma unroll
      for (int pp=0; pp<2; ++pp) {
        int pl = base_[li] + b8*mul_[li] + lg*2 + pp;   // in-bounds even if unused
        #pragma unroll
        for (int s2=0; s2<2; ++s2) {
          int hcol = cs*32 + s2*16 + col0;
          w36[li][pp][s2] = *(const bf16x4*)(wx4 + ((wbT+pl)<<9) + hcol*4);
        }
      }
    }
  }

  stage_B<512,256,264>(Upt, Blds, tid);
  __syncthreads();

  // ---------- n=1: A from leaf h (global); out -> LDS rows 0..31
  #pragma unroll
  for (int mi=0; mi<2; ++mi) {
    const int mt = rg + mi*2;
    const int rr = lane&15;
    int plA = 255 + b8*32 + mt*8 + (rr>>1);
    const bf16_t* hp = hg + (hb + 2*plA + 1 + (rr&1))*128 + lg*8;
    bf16x8 a[4];
    #pragma unroll
    for (int ks=0; ks<4; ++ks) a[ks] = *(const bf16x8*)(hp + ks*32);

    f32x4 acc[8];
    #pragma unroll
    for (int gs=0; gs<8; ++gs) acc[gs] = (f32x4){0.f,0.f,0.f,0.f};
    mfma8_lds(Blds, a, cs, lg, col0, acc);

    #pragma unroll
    for (int pp=0; pp<2; ++pp) {
      int pj = mt*8 + lg*2 + pp;
      #pragma unroll
      for (int s2=0; s2<2; ++s2) {
        int hcol = cs*32 + s2*16 + col0;
        float hn, cn;
        epi_one(acc, pp, s2, w1[mi][pp][s2],
                c1[mi][pp][s2].x, c1[mi][pp][s2].y, hn, cn);
        st_c[pj][hcol] = (bf16_t)cn;
        st_h[pj][hcol] = (bf16_t)hn;
      }
    }
  }
  __syncthreads();

  // ---------- n=2: children rows 0..31 (LDS); out rows 32..47
  {
    const int rr = lane&15;
    bf16x8 a[4];
    #pragma unroll
    for (int ks=0; ks<4; ++ks)
      a[ks] = *(const bf16x8*)(&st_h[rg*16 + rr][ks*32 + lg*8]);

    f32x4 acc[8];
    #pragma unroll
    for (int gs=0; gs<8; ++gs) acc[gs] = (f32x4){0.f,0.f,0.f,0.f};
    mfma8_lds(Blds, a, cs, lg, col0, acc);

    #pragma unroll
    for (int pp=0; pp<2; ++pp) {
      int pj = rg*8 + lg*2 + pp;                 // [0,16)
      #pragma unroll
      for (int s2=0; s2<2; ++s2) {
        int hcol = cs*32 + s2*16 + col0;
        float hn, cn;
        epi_one(acc, pp, s2, w2[pp][s2],
                (float)st_c[2*pj][hcol], (float)st_c[2*pj+1][hcol], hn, cn);
        st_c[32+pj][hcol] = (bf16_t)cn;
        st_h[32+pj][hcol] = (bf16_t)hn;
      }
    }
  }
  __syncthreads();

  // ---------- n=3..6: rowgroup 0 only; LDS state; n=6 -> global (hg + c2)
  #pragma unroll
  for (int li=0; li<4; ++li) {
    if (rg == 0) {
      const int Pn = Pn_[li];
      const int rr = lane&15;
      int r2 = (rr < 2*Pn) ? rr : 0;
      bf16x8 a[4];
      #pragma unroll
      for (int ks=0; ks<4; ++ks)
        a[ks] = *(const bf16x8*)(&st_h[cb_[li] + r2][ks*32 + lg*8]);

      f32x4 acc[8];
      #pragma unroll
      for (int gs=0; gs<8; ++gs) acc[gs] = (f32x4){0.f,0.f,0.f,0.f};
      mfma8_lds(Blds, a, cs, lg, col0, acc);

      #pragma unroll
      for (int pp=0; pp<2; ++pp) {
        int pj = lg*2 + pp;
        if (pj < Pn) {
          int pl = base_[li] + b8*mul_[li] + pj;
          #pragma unroll
          for (int s2=0; s2<2; ++s2) {
            int hcol = cs*32 + s2*16 + col0;
            float hn, cn;
            epi_one(acc, pp, s2, w36[li][pp][s2],
                    (float)st_c[cb_[li]+2*pj][hcol], (float)st_c[cb_[li]+2*pj+1][hcol],
                    hn, cn);
            if (li < 3) {
              st_c[ob_[li]+pj][hcol] = (bf16_t)cn;
              st_h[ob_[li]+pj][hcol] = (bf16_t)hn;
            } else {
              // order-6 -> global: hg + c2[parent of this node]
              int pc = pl - 1;
              c2[((wbT + (pc>>1))<<8) + hcol*2 + (pc&1)] = cn;
              hg[(hb+pl)*128 + hcol] = (bf16_t)hn;
            }
          }
        }
      }
    }
    __syncthreads();
  }
}

// =================== kernel 3: levels 7..9 + root head (1 block/tree) =========
__global__ __launch_bounds__(512, 2) void k_tail(
    const bf16_t* __restrict__ Upt, const bf16_t* __restrict__ wx4,
    const bf16_t* __restrict__ hg, const float* __restrict__ c2,
    const float* __restrict__ Wm, const float* __restrict__ bm,
    const float* __restrict__ Wv, const float* __restrict__ bv,
    const float* __restrict__ eps, float* __restrict__ out)
{
  __shared__ __align__(16) char Blds[135168];
  __shared__ __align__(16) bf16_t st_h[6][132];
  __shared__ float st_c[6][132];
  __shared__ float hs[128];
  const int tid = threadIdx.x, wave = tid>>6, lane = tid&63;
  const int rg = wave>>2, cs = wave&3, lg = lane>>4, col0 = lane&15;
  const int tree = blockIdx.x;
  const size_t hb = (size_t)tree*1023, wbT = (size_t)tree*511;

  const int Pn_[3] = {4, 2, 1};
  const int pb_[3] = {3, 1, 0};     // parent local base

  // upfront operand burst (rg0 does all the level work)
  bf16x4 wt[3][2][2]; float2 c7[2][2];
  if (rg == 0) {
    #pragma unroll
    for (int li=0; li<3; ++li) {
      #pragma unroll
      for (int pp=0; pp<2; ++pp) {
        int pl = pb_[li] + lg*2 + pp;
        if (pl > 6) pl = 6;                      // clamp (unused lanes)
        #pragma unroll
        for (int s2=0; s2<2; ++s2) {
          int hcol = cs*32 + s2*16 + col0;
          wt[li][pp][s2] = *(const bf16x4*)(wx4 + ((wbT+pl)<<9) + hcol*4);
        }
      }
    }
    #pragma unroll
    for (int pp=0; pp<2; ++pp) {
      int pl = 3 + lg*2 + pp;
      if (pl > 6) pl = 6;
      #pragma unroll
      for (int s2=0; s2<2; ++s2) {
        int hcol = cs*32 + s2*16 + col0;
        c7[pp][s2] = *(const float2*)(c2 + ((wbT+pl)<<8) + hcol*2);
      }
    }
  }

  stage_B<512,256,264>(Upt, Blds, tid);
  __syncthreads();

  #pragma unroll
  for (int li=0; li<3; ++li) {
    if (rg == 0) {
      const int Pn = Pn_[li];
      const int rr = lane&15;
      int r2 = (rr < 2*Pn) ? rr : 0;
      bf16x8 a[4];
      if (li == 0) {
        const bf16_t* hp = hg + (hb + 7 + r2)*128 + lg*8;   // order-6 children
        #pragma unroll
        for (int ks=0; ks<4; ++ks) a[ks] = *(const bf16x8*)(hp + ks*32);
      } else {
        int crow = (li == 1) ? r2 : (4 + ((rr < 2) ? rr : 0));
        #pragma unroll
        for (int ks=0; ks<4; ++ks)
          a[ks] = *(const bf16x8*)(&st_h[crow][ks*32 + lg*8]);
      }

      f32x4 acc[8];
      #pragma unroll
      for (int gs=0; gs<8; ++gs) acc[gs] = (f32x4){0.f,0.f,0.f,0.f};
      mfma8_lds(Blds, a, cs, lg, col0, acc);

      #pragma unroll
      for (int pp=0; pp<2; ++pp) {
        int pj = lg*2 + pp;
        if (pj < Pn) {
          #pragma unroll
          for (int s2=0; s2<2; ++s2) {
            int hcol = cs*32 + s2*16 + col0;
            float clv, crv;
            if (li == 0)      { clv = c7[pp][s2].x;      crv = c7[pp][s2].y; }
            else if (li == 1) { clv = st_c[2*pj][hcol];  crv = st_c[2*pj+1][hcol]; }
            else              { clv = st_c[4][hcol];     crv = st_c[5][hcol]; }
            float hn, cn;
            epi_one(acc, pp, s2, wt[li][pp][s2], clv, crv, hn, cn);
            if (li == 0)      { st_c[pj][hcol] = cn;   st_h[pj][hcol] = (bf16_t)hn; }
            else if (li == 1) { st_c[4+pj][hcol] = cn; st_h[4+pj][hcol] = (bf16_t)hn; }
            else              { hs[hcol] = hn; }
          }
        }
      }
    }
    __syncthreads();
  }

  // fused root head
  if (tid < 64) {
    const int j = tid;
    float am = 0.f, av = 0.f;
    #pragma unroll 4
    for (int i=0;i<128;++i) {
      float hv = hs[i];
      am += hv*Wm[i*64+j];
      av += hv*Wv[i*64+j];
    }
    float zm = am + bm[j];
    float zv = av + bv[j];
    int idx = tree*64 + j;
    out[idx]        = zm + eps[idx]*__expf(0.5f*zv);
    out[2048 + idx] = zm;
    out[4096 + idx] = zv;
  }
}

// =================== host launcher ============================================
extern "C" void kernel_launch(void* const* d_in, const int* in_sizes, int n_in,
                              void* d_out, int out_size, void* d_ws, size_t ws_size,
                              hipStream_t stream) {
  const int*   features = (const int*)  d_in[0];
  const int*   vocabs   = (const int*)  d_in[1];
  // d_in[2..5]: static topology (derived in-kernel)
  const float* eps      = (const float*)d_in[6];
  const float* emb_res  = (const float*)d_in[7];
  const float* emb_leaf = (const float*)d_in[8];
  const float* W_leaf   = (const float*)d_in[9];
  const float* b_leaf   = (const float*)d_in[10];
  const float* W_iou    = (const float*)d_in[11];
  const float* b_iou    = (const float*)d_in[12];
  const float* U_iou    = (const float*)d_in[13];
  const float* W_f      = (const float*)d_in[14];
  const float* b_f      = (const float*)d_in[15];
  const float* U_f      = (const float*)d_in[16];
  const float* Wm       = (const float*)d_in[17];
  const float* bm       = (const float*)d_in[18];
  const float* Wv       = (const float*)d_in[19];
  const float* bv       = (const float*)d_in[20];

  char* wsb = (char*)d_ws;
  bf16_t* hg  = (bf16_t*)wsb;                         // [NNODES][128] bf16
  float*  c2  = (float*)(wsb + 8388608);              // [NINT][128][2] f32 (child-pair c per parent)
  bf16_t* wx4 = (bf16_t*)(wsb + 8388608 + 16777216);  // [NINT][128][4] bf16 (i,o,u,f)
  bf16_t* Upt = (bf16_t*)(wsb + 8388608 + 16777216 + 16777216);  // [512][128] bf16
  float* out = (float*)d_out;

  k_prep_leaf<<<256, 1024, 0, stream>>>(features, vocabs, emb_res, emb_leaf,
                                        W_iou, b_iou, W_f, b_f, U_iou, U_f,
                                        W_leaf, b_leaf, wx4, hg, c2, Upt);
  k_levels<<<256, 512, 0, stream>>>(Upt, wx4, hg, c2);
  k_tail<<<TREES, 512, 0, stream>>>(Upt, wx4, hg, c2,
                                    Wm, bm, Wv, bv, eps, out);
}

// Round 14
// 95.341 us; speedup vs baseline: 1.3224x; 1.3224x over previous
//
#include <hip/hip_runtime.h>

#define TREES 32
#define NIPT  511
#define NINT  (TREES*NIPT)      // 16352
#define VLEAF 5000

typedef __bf16 bf16_t;
typedef bf16_t bf16x4 __attribute__((ext_vector_type(4)));
typedef bf16_t bf16x8 __attribute__((ext_vector_type(8)));
typedef float  f32x4  __attribute__((ext_vector_type(4)));

__device__ __forceinline__ float sigf(float x) { return 1.0f/(1.0f+__expf(-x)); }
__device__ __forceinline__ float tanh_fast(float x) { return 2.0f/(1.0f+__expf(-2.0f*x)) - 1.0f; }

__device__ __forceinline__ bf16x8 to_bf16x8(const float* p) {
  float4 a = *(const float4*)p;
  float4 b = *(const float4*)(p+4);
  bf16x8 r;
  r[0]=(bf16_t)a.x; r[1]=(bf16_t)a.y; r[2]=(bf16_t)a.z; r[3]=(bf16_t)a.w;
  r[4]=(bf16_t)b.x; r[5]=(bf16_t)b.y; r[6]=(bf16_t)b.z; r[7]=(bf16_t)b.w;
  return r;
}
__device__ __forceinline__ bf16x8 zero_bf16x8() {
  bf16x8 r;
  #pragma unroll
  for (int i=0;i<8;++i) r[i]=(bf16_t)0.0f;
  return r;
}
__device__ __forceinline__ bf16x8 ldsB(const char* lds, int col, int kb, int rowb) {
  return *(const bf16x8*)(lds + col*rowb + kb);
}

// ---- per-wave U fragments (fp32 source; compiler may remat from L2 — accepted, R9-proven)
__device__ __forceinline__ void load_breg(const float* __restrict__ U_iou,
                                          const float* __restrict__ U_f,
                                          int cs, int lg, int col0, bf16x8 breg[8][4]) {
  #pragma unroll
  for (int gs=0; gs<8; ++gs) {
    int col = (gs>>1)*128 + cs*32 + (gs&1)*16 + col0;
    const float* src; int ld;
    if (col < 384) { src = U_iou + col; ld = 384; }
    else           { src = U_f + (col-384); ld = 128; }
    #pragma unroll
    for (int ks=0; ks<4; ++ks) {
      #pragma unroll
      for (int i=0;i<8;++i) breg[gs][ks][i] = (bf16_t)src[(ks*32 + lg*8 + i)*ld];
    }
  }
}

__device__ __forceinline__ void mfma8(const bf16x8 a[4], const bf16x8 breg[8][4], f32x4 acc[8]) {
  #pragma unroll
  for (int ks=0; ks<4; ++ks) {
    #pragma unroll
    for (int gs=0; gs<8; ++gs)
      acc[gs] = __builtin_amdgcn_mfma_f32_16x16x32_bf16(a[ks], breg[gs][ks], acc[gs], 0,0,0);
  }
}

// LSTM combine: acc gs = {i:0,1 | o:2,3 | u:4,5 | f:6,7}, rows 2pp,2pp+1 = children L,R
__device__ __forceinline__ void lstm_epi(const f32x4 acc[8], const bf16x4 w4[2][2],
                                         const float2 cp[2][2],
                                         float hn[2][2], float cn[2][2]) {
  #pragma unroll
  for (int pp=0; pp<2; ++pp) {
    #pragma unroll
    for (int s2=0; s2<2; ++s2) {
      float iv = acc[s2][2*pp]   + acc[s2][2*pp+1]   + (float)w4[pp][s2][0];
      float ov = acc[2+s2][2*pp] + acc[2+s2][2*pp+1] + (float)w4[pp][s2][1];
      float uv = acc[4+s2][2*pp] + acc[4+s2][2*pp+1] + (float)w4[pp][s2][2];
      float wf = (float)w4[pp][s2][3];
      float fl = sigf(acc[6+s2][2*pp]   + wf);
      float fr = sigf(acc[6+s2][2*pp+1] + wf);
      float cf = fl*cp[pp][s2].x + fr*cp[pp][s2].y;
      float c  = sigf(iv)*tanh_fast(uv) + cf;
      cn[pp][s2] = c;
      hn[pp][s2] = sigf(ov)*tanh_fast(c);
    }
  }
}

// ---- staging (1024-thread variants): fp32 src columns -> bf16 N-major LDS ----
__device__ __forceinline__ void stage_WU_1k(const float* __restrict__ Wa, int lda,
                                            const float* __restrict__ Wb, int ldb,
                                            char* lds, int tid) {
  int col = tid & 511, kh = tid >> 9;            // two threads split each column's k
  const float* src; int ld;
  if (col < 384) { src = Wa + col; ld = lda; }
  else           { src = Wb + (col-384); ld = ldb; }
  const int kbase = kh*64;
  #pragma unroll
  for (int k0 = 0; k0 < 64; k0 += 8) {
    bf16x8 r;
    #pragma unroll
    for (int i=0;i<8;++i) r[i] = (bf16_t)src[(kbase+k0+i)*ld];
    *(bf16x8*)(lds + col*264 + (kbase+k0)*2) = r;
  }
}
__device__ __forceinline__ void stage_WL_1k(const float* __restrict__ W_leaf, char* lds, int tid) {
  int col = tid & 511, kh = tid >> 9;
  if (col < 384) {
    int cm = col < 128 ? col : col + 128;        // [gi,gg,go] from [gi,gf,gg,go]
    const int kbase = kh*96;
    #pragma unroll
    for (int k0 = 0; k0 < 96; k0 += 8) {
      bf16x8 r;
      #pragma unroll
      for (int i=0;i<8;++i) {
        int k = kbase+k0+i;
        r[i] = (bf16_t)W_leaf[(k>>6)*32768 + (k&63)*512 + cm];
      }
      *(bf16x8*)(lds + col*392 + (kbase+k0)*2) = r;
    }
  }
}

// =================== kernel 1: prep (blocks 0-127) | leaf (blocks 128-255) ====
// 1024 threads = 16 waves (4 rowgroups x 4 col-slices), 128 rows per block
__global__ __launch_bounds__(1024) void k_prep_leaf(
    const int* __restrict__ features, const int* __restrict__ vocabs,
    const float* __restrict__ emb_res, const float* __restrict__ emb_leaf,
    const float* __restrict__ W_iou, const float* __restrict__ b_iou,
    const float* __restrict__ W_f, const float* __restrict__ b_f,
    const float* __restrict__ W_leaf, const float* __restrict__ b_leaf,
    bf16_t* __restrict__ wx4, bf16_t* __restrict__ hg, float* __restrict__ c2)
{
  __shared__ __align__(16) char Blds[150528];
  const int tid = threadIdx.x, wave = tid>>6, lane = tid&63;
  const int rg = wave>>2, cs = wave&3, lg = lane>>4, col0 = lane&15;

  if (blockIdx.x < 128) {
    // ===== prep: wx4[ci][hcol][g] = bf16(emb@[W_iou|W_f]+bias), g={i,o,u,f}=cs
    stage_WU_1k(W_iou, 384, W_f, 128, Blds, tid);
    __syncthreads();
    #pragma unroll
    for (int mi=0; mi<2; ++mi) {
      int mt = rg + mi*4;
      int row0 = blockIdx.x*128 + mt*16;
      int rowA = row0 + (lane&15);
      if (rowA >= NINT) rowA = NINT-1;
      unsigned tree = (unsigned)rowA / 511u;
      int local = rowA - tree*511u;
      int feat = features[tree*1023 + local];
      const float* ep = emb_res + (size_t)feat*128 + lg*8;

      bf16x8 a[4];
      #pragma unroll
      for (int ks=0; ks<4; ++ks) a[ks] = to_bf16x8(ep + ks*32);

      f32x4 acc[8];
      #pragma unroll
      for (int j=0;j<8;++j) acc[j] = (f32x4){0.f,0.f,0.f,0.f};
      #pragma unroll
      for (int ks=0; ks<4; ++ks) {
        #pragma unroll
        for (int j=0; j<8; ++j) {
          bf16x8 b = ldsB(Blds, cs*128 + j*16 + col0, ks*64 + lg*16, 264);
          acc[j] = __builtin_amdgcn_mfma_f32_16x16x32_bf16(a[ks], b, acc[j], 0,0,0);
        }
      }
      #pragma unroll
      for (int j=0; j<8; ++j) {
        int hcol = j*16 + col0;
        int c = cs*128 + hcol;
        float bias = (c < 384) ? b_iou[c] : b_f[c-384];
        #pragma unroll
        for (int r=0; r<4; ++r) {
          int ci = row0 + lg*4 + r;
          if (ci >= NINT) ci = NINT-1;
          wx4[(size_t)ci*512 + hcol*4 + cs] = (bf16_t)(acc[j][r] + bias);
        }
      }
    }
  } else {
    // ===== leaf: block-diag K=192 GEMM, N=384 [gi|gg|go]; writes hg + paired c2
    stage_WL_1k(W_leaf, Blds, tid);
    __syncthreads();
    #pragma unroll
    for (int mi=0; mi<2; ++mi) {
      int mt = rg + mi*4;
      const int base = (int)(blockIdx.x-128)*128 + mt*16;
      int rA = base + (lane&15);
      int treeA = rA>>9, loA = rA&511;
      int nodeA = treeA*1023 + 511 + loA;
      int kkA = vocabs[nodeA]-1;
      int featA = features[nodeA];
      const float* xp = emb_leaf + ((size_t)kkA*VLEAF + featA)*64;

      f32x4 acc[6];
      #pragma unroll
      for (int j=0;j<6;++j) acc[j] = (f32x4){0.f,0.f,0.f,0.f};
      #pragma unroll
      for (int ks=0; ks<6; ++ks) {
        int k0 = ks*32 + lg*8;
        bf16x8 a = ((k0>>6) == kkA) ? to_bf16x8(xp + (k0&63)) : zero_bf16x8();
        #pragma unroll
        for (int g=0; g<3; ++g) {
          #pragma unroll
          for (int s=0; s<2; ++s) {
            bf16x8 b = ldsB(Blds, g*128 + cs*32 + s*16 + col0, ks*64 + lg*16, 392);
            acc[g*2+s] = __builtin_amdgcn_mfma_f32_16x16x32_bf16(a, b, acc[g*2+s], 0,0,0);
          }
        }
      }
      #pragma unroll
      for (int r=0; r<4; ++r) {
        int L = base + lg*4 + r;
        int tree = L>>9, lo = L&511;
        int l = 511 + lo;
        int node = tree*1023 + l;
        int kk = vocabs[node]-1;
        const float* bl = b_leaf + kk*512;
        int pl = l - 1;
        size_t c2b = ((size_t)tree*511 + (pl>>1))*256;
        #pragma unroll
        for (int s=0; s<2; ++s) {
          int cc = cs*32 + s*16 + col0;
          float gi = acc[s][r]   + bl[cc];
          float gg = acc[2+s][r] + bl[256+cc];
          float go = acc[4+s][r] + bl[384+cc];
          float ck = sigf(gi)*tanh_fast(gg);
          float hk = sigf(go)*tanh_fast(ck);
          c2[c2b + cc*2 + (pl&1)] = ck;
          hg[(size_t)node*128+cc] = (bf16_t)hk;
        }
      }
    }
  }
}

// =================== kernel 2: levels 1..6, orders 1-5 in LDS (R9 structure) ==
// 256 blocks (8 per tree), 32 order-1 parents each; U via breg (L2-backed)
__global__ __launch_bounds__(512, 2) void k_levels(
    const float* __restrict__ U_iou, const float* __restrict__ U_f,
    const bf16_t* __restrict__ wx4, bf16_t* __restrict__ hg, float* __restrict__ c2)
{
  __shared__ __align__(16) bf16_t st_h[48][136];
  __shared__ float st_c[48][132];
  const int tid = threadIdx.x, wave = tid>>6, lane = tid&63;
  const int rg = wave>>2, cs = wave&3, lg = lane>>4, col0 = lane&15;
  const int blk = blockIdx.x, tree = blk>>3, b8 = blk&7;

  bf16x8 breg[8][4];
  load_breg(U_iou, U_f, cs, lg, col0, breg);

  // ---------- n=1: A = leaf h (global), c = c2 (global); out -> st rows 0..31
  #pragma unroll
  for (int mi=0; mi<2; ++mi) {
    const int mt = rg + mi*2;
    int rr = lane&15;
    int fp = blk*32 + mt*8 + (rr>>1);          // flat order-1 parent
    int loA = fp & 255;
    int chA = tree*1023 + 2*(255+loA) + 1 + (rr&1);
    const bf16_t* hp = hg + (size_t)chA*128 + lg*8;
    bf16x8 a[4];
    #pragma unroll
    for (int ks=0; ks<4; ++ks) a[ks] = *(const bf16x8*)(hp + ks*32);

    bf16x4 w4[2][2]; float2 cp[2][2]; int pib[2];
    #pragma unroll
    for (int pp=0; pp<2; ++pp) {
      int pj = mt*8 + lg*2 + pp;
      pib[pp] = pj;
      size_t ci = (size_t)tree*511 + 255 + (b8*32 + pj);
      #pragma unroll
      for (int s2=0; s2<2; ++s2) {
        int hcol = cs*32 + s2*16 + col0;
        w4[pp][s2] = *(const bf16x4*)(wx4 + ci*512 + hcol*4);
        cp[pp][s2] = *(const float2*)(c2 + ci*256 + hcol*2);
      }
    }

    f32x4 acc[8];
    #pragma unroll
    for (int gs=0; gs<8; ++gs) acc[gs] = (f32x4){0.f,0.f,0.f,0.f};
    mfma8(a, breg, acc);
    float hn[2][2], cn[2][2];
    lstm_epi(acc, w4, cp, hn, cn);
    #pragma unroll
    for (int pp=0; pp<2; ++pp) {
      #pragma unroll
      for (int s2=0; s2<2; ++s2) {
        int hcol = cs*32 + s2*16 + col0;
        st_c[pib[pp]][hcol] = cn[pp][s2];
        st_h[pib[pp]][hcol] = (bf16_t)hn[pp][s2];
      }
    }
  }
  __syncthreads();

  // ---------- n=2: children = st rows 0..31; out -> st rows 32..47
  {
    const int mt2 = rg;
    int rr = lane&15;
    int crow = mt2*16 + rr;
    bf16x8 a[4];
    #pragma unroll
    for (int ks=0; ks<4; ++ks)
      a[ks] = *(const bf16x8*)(&st_h[crow][ks*32 + lg*8]);

    bf16x4 w4[2][2]; float2 cp[2][2]; int pnode[2];
    #pragma unroll
    for (int pp=0; pp<2; ++pp) {
      int pj = mt2*8 + lg*2 + pp;                // [0,16)
      pnode[pp] = 32 + pj;
      int f2 = blk*16 + pj;
      int tr2 = f2>>7, lo = f2&127;
      int plocal = 127+lo;
      size_t wb = ((size_t)tr2*511 + plocal)*512;
      #pragma unroll
      for (int s2=0; s2<2; ++s2) {
        int hcol = cs*32 + s2*16 + col0;
        w4[pp][s2] = *(const bf16x4*)(wx4 + wb + hcol*4);
        cp[pp][s2] = make_float2(st_c[2*pj][hcol], st_c[2*pj+1][hcol]);
      }
    }

    f32x4 acc[8];
    #pragma unroll
    for (int gs=0; gs<8; ++gs) acc[gs] = (f32x4){0.f,0.f,0.f,0.f};
    mfma8(a, breg, acc);
    float hn[2][2], cn[2][2];
    lstm_epi(acc, w4, cp, hn, cn);
    #pragma unroll
    for (int pp=0; pp<2; ++pp) {
      #pragma unroll
      for (int s2=0; s2<2; ++s2) {
        int hcol = cs*32 + s2*16 + col0;
        st_c[pnode[pp]][hcol] = cn[pp][s2];
        st_h[pnode[pp]][hcol] = (bf16_t)hn[pp][s2];
      }
    }
  }
  __syncthreads();

  // ---------- n=3..6: rowgroup 0 only; st->st (li<3) or st->global (li=3)
  const int Pn_[4]   = {8, 4, 2, 1};
  const int cb_[4]   = {32, 0, 8, 12};     // child st row base
  const int ob_[4]   = {0, 8, 12, 0};      // out st row base (li<3)
  const int base_[4] = {63, 31, 15, 7};    // parent plocal base
  const int mul_[4]  = {8, 4, 2, 1};       // parents per block
  #pragma unroll
  for (int li=0; li<4; ++li) {
    if (rg == 0) {
      const int Pn = Pn_[li];
      int rr = lane&15;
      int r2 = (rr < 2*Pn) ? rr : 0;
      bf16x8 a[4];
      #pragma unroll
      for (int ks=0; ks<4; ++ks)
        a[ks] = *(const bf16x8*)(&st_h[cb_[li] + r2][ks*32 + lg*8]);

      bf16x4 w4[2][2]; float2 cp[2][2]; int pj[2], plocal[2];
      #pragma unroll
      for (int pp=0; pp<2; ++pp) {
        pj[pp] = lg*2 + pp;
        plocal[pp] = base_[li] + b8*mul_[li] + pj[pp];
        size_t wb = ((size_t)tree*511 + plocal[pp])*512;
        int cr0 = cb_[li] + 2*pj[pp];
        #pragma unroll
        for (int s2=0; s2<2; ++s2) {
          int hcol = cs*32 + s2*16 + col0;
          w4[pp][s2] = *(const bf16x4*)(wx4 + wb + hcol*4);
          cp[pp][s2] = make_float2(st_c[cr0][hcol], st_c[cr0+1][hcol]);
        }
      }

      f32x4 acc[8];
      #pragma unroll
      for (int gs=0; gs<8; ++gs) acc[gs] = (f32x4){0.f,0.f,0.f,0.f};
      mfma8(a, breg, acc);
      float hn[2][2], cn[2][2];
      lstm_epi(acc, w4, cp, hn, cn);
      #pragma unroll
      for (int pp=0; pp<2; ++pp) {
        if (pj[pp] < Pn) {
          #pragma unroll
          for (int s2=0; s2<2; ++s2) {
            int hcol = cs*32 + s2*16 + col0;
            if (li < 3) {
              st_c[ob_[li] + pj[pp]][hcol] = cn[pp][s2];
              st_h[ob_[li] + pj[pp]][hcol] = (bf16_t)hn[pp][s2];
            } else {
              // order-6 -> global (plocal = 7 + b8)
              int pl = plocal[pp] - 1;
              c2[((size_t)tree*511 + (pl>>1))*256 + hcol*2 + (pl&1)] = cn[pp][s2];
              hg[((size_t)tree*1023 + plocal[pp])*128 + hcol] = (bf16_t)hn[pp][s2];
            }
          }
        }
      }
    }
    __syncthreads();
  }
}

// =================== kernel 3: levels 7..9 + root head (1 block/tree) =========
__global__ __launch_bounds__(512, 2) void k_tail(
    const float* __restrict__ U_iou, const float* __restrict__ U_f,
    const bf16_t* __restrict__ wx4, bf16_t* __restrict__ hg, float* __restrict__ c2,
    const float* __restrict__ Wm, const float* __restrict__ bm,
    const float* __restrict__ Wv, const float* __restrict__ bv,
    const float* __restrict__ eps, float* __restrict__ out)
{
  __shared__ float hs[128];
  const int tid = threadIdx.x, wave = tid>>6, lane = tid&63;
  const int rg = wave>>2, cs = wave&3, lg = lane>>4, col0 = lane&15;
  const int tree = blockIdx.x;

  bf16x8 breg[8][4];
  load_breg(U_iou, U_f, cs, lg, col0, breg);

  const int Pn_[3]  = {4, 2, 1};
  const int chb_[3] = {7, 3, 1};     // child local base
  const int pb_[3]  = {3, 1, 0};     // parent local base
  #pragma unroll
  for (int li=0; li<3; ++li) {
    if (rg == 0) {
      const int Pn = Pn_[li];
      int rr = lane&15;
      int r2 = (rr < 2*Pn) ? rr : 0;
      const bf16_t* hp = hg + ((size_t)tree*1023 + chb_[li] + r2)*128 + lg*8;
      bf16x8 a[4];
      #pragma unroll
      for (int ks=0; ks<4; ++ks) a[ks] = *(const bf16x8*)(hp + ks*32);

      bf16x4 w4[2][2]; float2 cp[2][2]; int pj[2], plocal[2];
      #pragma unroll
      for (int pp=0; pp<2; ++pp) {
        pj[pp] = lg*2 + pp;
        plocal[pp] = pb_[li] + pj[pp];
        size_t ci = (size_t)tree*511 + plocal[pp];
        #pragma unroll
        for (int s2=0; s2<2; ++s2) {
          int hcol = cs*32 + s2*16 + col0;
          w4[pp][s2] = *(const bf16x4*)(wx4 + ci*512 + hcol*4);
          cp[pp][s2] = *(const float2*)(c2 + ci*256 + hcol*2);
        }
      }

      f32x4 acc[8];
      #pragma unroll
      for (int gs=0; gs<8; ++gs) acc[gs] = (f32x4){0.f,0.f,0.f,0.f};
      mfma8(a, breg, acc);
      float hn[2][2], cn[2][2];
      lstm_epi(acc, w4, cp, hn, cn);
      #pragma unroll
      for (int pp=0; pp<2; ++pp) {
        if (pj[pp] < Pn) {
          #pragma unroll
          for (int s2=0; s2<2; ++s2) {
            int hcol = cs*32 + s2*16 + col0;
            if (li < 2) {
              int pl = plocal[pp] - 1;
              c2[((size_t)tree*511 + (pl>>1))*256 + hcol*2 + (pl&1)] = cn[pp][s2];
              hg[((size_t)tree*1023 + plocal[pp])*128 + hcol] = (bf16_t)hn[pp][s2];
            } else {
              hs[hcol] = hn[pp][s2];       // root h -> LDS only
            }
          }
        }
      }
    }
    __threadfence_block();
    __syncthreads();
  }

  // fused root head
  if (tid < 64) {
    const int j = tid;
    float am = 0.f, av = 0.f;
    #pragma unroll 4
    for (int i=0;i<128;++i) {
      float hv = hs[i];
      am += hv*Wm[i*64+j];
      av += hv*Wv[i*64+j];
    }
    float zm = am + bm[j];
    float zv = av + bv[j];
    int idx = tree*64 + j;
    out[idx]        = zm + eps[idx]*__expf(0.5f*zv);
    out[2048 + idx] = zm;
    out[4096 + idx] = zv;
  }
}

// =================== host launcher ============================================
extern "C" void kernel_launch(void* const* d_in, const int* in_sizes, int n_in,
                              void* d_out, int out_size, void* d_ws, size_t ws_size,
                              hipStream_t stream) {
  const int*   features = (const int*)  d_in[0];
  const int*   vocabs   = (const int*)  d_in[1];
  // d_in[2..5]: static topology (derived in-kernel)
  const float* eps      = (const float*)d_in[6];
  const float* emb_res  = (const float*)d_in[7];
  const float* emb_leaf = (const float*)d_in[8];
  const float* W_leaf   = (const float*)d_in[9];
  const float* b_leaf   = (const float*)d_in[10];
  const float* W_iou    = (const float*)d_in[11];
  const float* b_iou    = (const float*)d_in[12];
  const float* U_iou    = (const float*)d_in[13];
  const float* W_f      = (const float*)d_in[14];
  const float* b_f      = (const float*)d_in[15];
  const float* U_f      = (const float*)d_in[16];
  const float* Wm       = (const float*)d_in[17];
  const float* bm       = (const float*)d_in[18];
  const float* Wv       = (const float*)d_in[19];
  const float* bv       = (const float*)d_in[20];

  char* wsb = (char*)d_ws;
  bf16_t* hg  = (bf16_t*)wsb;                         // [NNODES][128] bf16
  float*  c2  = (float*)(wsb + 8388608);              // [NINT][128][2] f32 (child-pair c per parent)
  bf16_t* wx4 = (bf16_t*)(wsb + 8388608 + 16777216);  // [NINT][128][4] bf16 (i,o,u,f)
  float* out = (float*)d_out;

  k_prep_leaf<<<256, 1024, 0, stream>>>(features, vocabs, emb_res, emb_leaf,
                                        W_iou, b_iou, W_f, b_f,
                                        W_leaf, b_leaf, wx4, hg, c2);
  k_levels<<<256, 512, 0, stream>>>(U_iou, U_f, wx4, hg, c2);
  k_tail<<<TREES, 512, 0, stream>>>(U_iou, U_f, wx4, hg, c2,
                                    Wm, bm, Wv, bv, eps, out);
}